// Round 1
// 964.594 us; speedup vs baseline: 1.2337x; 1.2337x over previous
//
#include <hip/hip_runtime.h>
#include <hip/hip_bf16.h>

typedef unsigned short u16;
typedef __attribute__((ext_vector_type(8))) short short8;
typedef __attribute__((ext_vector_type(4))) short short4v;
typedef __attribute__((ext_vector_type(4))) float f32x4;

__device__ __forceinline__ u16 f2bf(float f) {
  union { float f; unsigned int i; } v; v.f = f;
  unsigned int x = v.i;
  unsigned int r = x + 0x7fff + ((x >> 16) & 1);
  return (u16)(r >> 16);
}
__device__ __forceinline__ float bf2f(u16 u) {
  union { unsigned int i; float f; } v; v.i = ((unsigned int)u) << 16; return v.f;
}

// ---------------- transpose+convert: src fp32 [K][N] -> dst bf16 [N][K] ----------------
struct TDesc { const float* src; u16* dst; int K; int N; };
struct TDescs { TDesc d[14]; };

__launch_bounds__(256)
__global__ void k_transpose(TDescs td) {
  TDesc t = td.d[blockIdx.z];
  int tk = blockIdx.y * 32, tn = blockIdx.x * 32;
  if (tk >= t.K || tn >= t.N) return;
  __shared__ u16 tile[32][33];
  int tx = threadIdx.x & 31, ty = threadIdx.x >> 5; // 32 x 8
  for (int i = 0; i < 32; i += 8)
    tile[ty + i][tx] = f2bf(t.src[(long)(tk + ty + i) * t.N + tn + tx]);
  __syncthreads();
  for (int i = 0; i < 32; i += 8)
    t.dst[(long)(tn + ty + i) * t.K + tk + tx] = tile[tx][ty + i];
}

// ---------------- layernorm of a and s (rows of 768), + s->bf16 ----------------
__launch_bounds__(256)
__global__ void k_layernorm(const float* __restrict__ a, const float* __restrict__ s,
                            const float* __restrict__ sg1, const float* __restrict__ sg2,
                            float* __restrict__ ln_a, u16* __restrict__ snb1,
                            u16* __restrict__ snb2, u16* __restrict__ sb) {
  const int row = blockIdx.x, tid = threadIdx.x;
  const float* ar = a + (long)row * 768;
  const float* sr = s + (long)row * 768;
  float av[3], sv[3];
  float sa = 0.f, sa2 = 0.f, ss = 0.f, ss2 = 0.f;
  for (int i = 0; i < 3; i++) {
    float x = ar[tid + i * 256]; av[i] = x; sa += x; sa2 += x * x;
    float y = sr[tid + i * 256]; sv[i] = y; ss += y; ss2 += y * y;
  }
  __shared__ float red[4][4];
  for (int off = 32; off > 0; off >>= 1) {
    sa += __shfl_down(sa, off); sa2 += __shfl_down(sa2, off);
    ss += __shfl_down(ss, off); ss2 += __shfl_down(ss2, off);
  }
  if ((tid & 63) == 0) { int w = tid >> 6; red[w][0] = sa; red[w][1] = sa2; red[w][2] = ss; red[w][3] = ss2; }
  __syncthreads();
  sa  = red[0][0] + red[1][0] + red[2][0] + red[3][0];
  sa2 = red[0][1] + red[1][1] + red[2][1] + red[3][1];
  ss  = red[0][2] + red[1][2] + red[2][2] + red[3][2];
  ss2 = red[0][3] + red[1][3] + red[2][3] + red[3][3];
  const float n1 = 1.f / 768.f;
  float mua = sa * n1, vara = sa2 * n1 - mua * mua;
  float mus = ss * n1, vars = ss2 * n1 - mus * mus;
  float ra = rsqrtf(vara + 1e-5f), rs = rsqrtf(vars + 1e-5f);
  for (int i = 0; i < 3; i++) {
    int c = tid + i * 256;
    long idx = (long)row * 768 + c;
    ln_a[idx] = (av[i] - mua) * ra;
    float lns = (sv[i] - mus) * rs;
    snb1[idx] = f2bf(lns * sg1[c]);
    snb2[idx] = f2bf(lns * sg2[c]);
    sb[idx]   = f2bf(sv[i]);
  }
}

// ---------------- generic bf16 MFMA GEMM: C[M][N] = A[M][K] @ BT[N][K]^T ----------------
__launch_bounds__(256)
__global__ void k_gemm_bt(const u16* __restrict__ A, const u16* __restrict__ BT,
                          float* __restrict__ C, int M, int N, int K) {
  __shared__ u16 As[64][40];
  __shared__ u16 Bs[64][40];
  const int tid = threadIdx.x;
  const int n0 = blockIdx.x * 64, m0 = blockIdx.y * 64;
  const int wave = tid >> 6, lane = tid & 63;
  const int wr = (wave >> 1) * 32, wc = (wave & 1) * 32;
  const int lrow = lane & 15, quad = lane >> 4;
  const int ldr = tid >> 2, ldk = (tid & 3) * 8;
  f32x4 acc00 = {0,0,0,0}, acc01 = {0,0,0,0}, acc10 = {0,0,0,0}, acc11 = {0,0,0,0};
  const u16* Ap = A + (long)(m0 + ldr) * K + ldk;
  const u16* Bp = BT + (long)(n0 + ldr) * K + ldk;
  for (int k0 = 0; k0 < K; k0 += 32) {
    __syncthreads();
    *(short8*)&As[ldr][ldk] = *(const short8*)(Ap + k0);
    *(short8*)&Bs[ldr][ldk] = *(const short8*)(Bp + k0);
    __syncthreads();
    short8 a0 = *(const short8*)&As[wr + lrow][quad * 8];
    short8 a1 = *(const short8*)&As[wr + 16 + lrow][quad * 8];
    short8 b0 = *(const short8*)&Bs[wc + lrow][quad * 8];
    short8 b1 = *(const short8*)&Bs[wc + 16 + lrow][quad * 8];
    acc00 = __builtin_amdgcn_mfma_f32_16x16x32_bf16(a0, b0, acc00, 0, 0, 0);
    acc01 = __builtin_amdgcn_mfma_f32_16x16x32_bf16(a0, b1, acc01, 0, 0, 0);
    acc10 = __builtin_amdgcn_mfma_f32_16x16x32_bf16(a1, b0, acc10, 0, 0, 0);
    acc11 = __builtin_amdgcn_mfma_f32_16x16x32_bf16(a1, b1, acc11, 0, 0, 0);
  }
  const int row = m0 + wr + quad * 4;
  const int col = n0 + wc + lrow;
  for (int r = 0; r < 4; r++) {
    C[(long)(row + r) * N + col]           = acc00[r];
    C[(long)(row + r) * N + col + 16]      = acc01[r];
    C[(long)(row + r + 16) * N + col]      = acc10[r];
    C[(long)(row + r + 16) * N + col + 16] = acc11[r];
  }
}

// ---------------- ada_ln epilogue for both branches ----------------
__launch_bounds__(256)
__global__ void k_adaln2(const float* __restrict__ g1, const float* __restrict__ g2,
                         const float* __restrict__ ln_a, const float* __restrict__ bg1,
                         const float* __restrict__ bg2, u16* __restrict__ an1,
                         u16* __restrict__ at2) {
  int i = blockIdx.x * 256 + threadIdx.x;  // over 1024*768
  int c = i % 768; long m = i / 768;
  float lna = ln_a[i];
  float x1 = g1[m * 1536 + c], y1 = g1[m * 1536 + 768 + c];
  float x2 = g2[m * 1536 + c], y2 = g2[m * 1536 + 768 + c];
  float s1 = 1.f / (1.f + __expf(-(x1 + bg1[c])));
  float s2 = 1.f / (1.f + __expf(-(x2 + bg2[c])));
  an1[i] = f2bf(s1 * lna + y1);
  at2[i] = f2bf(s2 * lna + y2);
}

// ---------------- pair bias via MFMA: bf16 [H][N][N] = (LN(pair)*gp+bp) @ wp + beta ----------------
__launch_bounds__(256)
__global__ void k_pairbias(const float* __restrict__ pair, const float* __restrict__ beta,
                           const float* __restrict__ gp, const float* __restrict__ bp,
                           const float* __restrict__ wp, u16* __restrict__ biasb) {
  __shared__ u16 Xs[64][136];
  __shared__ u16 Wb[16][136];
  __shared__ float Mu[64], Rs[64];
  __shared__ float AB[2][16];
  const int tid = threadIdx.x;
  const long base = (long)blockIdx.x * 64;
  // weights -> LDS
  for (int i = tid; i < 2048; i += 256) {
    int c = i >> 4, h = i & 15;
    Wb[h][c] = f2bf(gp[c] * wp[i]);
  }
  if (tid < 32) {
    int h = tid & 15;
    float acc = 0.f;
    if (tid < 16) { for (int c = 0; c < 128; c++) acc += gp[c] * wp[c * 16 + h]; }
    else          { for (int c = 0; c < 128; c++) acc += bp[c] * wp[c * 16 + h]; }
    AB[tid >> 4][h] = acc;
  }
  // stage X: 4 lanes per element, 32 floats each, coalesced f32x4
  const int e = tid >> 2, r = tid & 3;
  const float* px = pair + (base + e) * 128 + r * 4;
  float sum = 0.f, sq = 0.f;
  for (int p = 0; p < 8; p++) {
    f32x4 x = *(const f32x4*)(px + p * 16);
    sum += x[0] + x[1] + x[2] + x[3];
    sq  += x[0]*x[0] + x[1]*x[1] + x[2]*x[2] + x[3]*x[3];
    short4v pk;
    pk[0] = (short)f2bf(x[0]); pk[1] = (short)f2bf(x[1]);
    pk[2] = (short)f2bf(x[2]); pk[3] = (short)f2bf(x[3]);
    *(short4v*)&Xs[e][r * 4 + p * 16] = pk;
  }
  sum += __shfl_xor(sum, 1); sum += __shfl_xor(sum, 2);
  sq  += __shfl_xor(sq, 1);  sq  += __shfl_xor(sq, 2);
  if (r == 0) {
    float mu = sum * (1.f / 128.f);
    float var = sq * (1.f / 128.f) - mu * mu;
    Mu[e] = mu; Rs[e] = rsqrtf(var + 1e-5f);
  }
  __syncthreads();
  // MFMA: each wave does 16 elements x 16 heads, K=128
  const int wave = tid >> 6, lane = tid & 63;
  const int m = lane & 15, quad = lane >> 4;
  const int erow = wave * 16;
  f32x4 acc = {0, 0, 0, 0};
  for (int k0 = 0; k0 < 128; k0 += 32) {
    short8 af = *(const short8*)&Xs[erow + m][k0 + quad * 8];
    short8 bf = *(const short8*)&Wb[m][k0 + quad * 8];
    acc = __builtin_amdgcn_mfma_f32_16x16x32_bf16(af, bf, acc, 0, 0, 0);
  }
  // epilogue: C layout col=lane&15 (=h), row=quad*4+reg (=element)
  const int h = lane & 15;
  const float Ahv = AB[0][h], Bhv = AB[1][h];
  const int e0 = erow + quad * 4;
  short4v outp;
  for (int rr = 0; rr < 4; rr++) {
    int ee = e0 + rr;
    float bt = beta[base + ee];
    float val = Rs[ee] * acc[rr] - Rs[ee] * Mu[ee] * Ahv + Bhv + bt;
    outp[rr] = (short)f2bf(val);
  }
  *(short4v*)&biasb[((long)h << 20) + base + e0] = outp;
}

// ---------------- attention: MFMA flash, 64 q-rows/block (4 waves x 16), 64-key tiles ----------------
// LDS rows padded to 72 bf16 (144 B = 36 dwords -> 4-bank step, ~conflict-free b128 reads).
// D=48 padded to 64: Ks cols 48..63 zeroed once; Q frag kk=1 quads 2,3 zero.
__launch_bounds__(256)
__global__ void k_attention(const float* __restrict__ qkvg, const float* __restrict__ bq,
                            const u16* __restrict__ biasb, float* __restrict__ o_out) {
  const int h = blockIdx.y;
  const int q0 = blockIdx.x * 64;
  __shared__ u16 Ks[2][64][72];   // [buf][key][d]
  __shared__ u16 Vt[2][48][72];   // [buf][d][key]  (transposed V)
  __shared__ u16 Ps[4][16][72];   // per-wave P tile [q][key]
  const int tid = threadIdx.x;
  const int w = tid >> 6, lane = tid & 63;
  const int lr = lane & 15, quad = lane >> 4;
  const float scale = 0.14433756729740643f;  // 1/sqrt(48)

  // zero K pad cols 48..63 for both buffers
  for (int i = tid; i < 2 * 64 * 16; i += 256) {
    int b = i >> 10, rr = (i >> 4) & 63, c = 48 + (i & 15);
    Ks[b][rr][c] = 0;
  }

  // Q fragments in registers (A-operand, rows = q0 + w*16 + lr)
  short8 qf0, qf1;
  {
    const int qrow = q0 + w * 16 + lr;
    const float* qp = qkvg + (long)qrow * 3072 + h * 48;
    const float* bqp = bq + h * 48;
    const int d0 = quad * 8;
#pragma unroll
    for (int i = 0; i < 8; i++)
      qf0[i] = (short)f2bf((qp[d0 + i] + bqp[d0 + i]) * scale);
    if (quad < 2) {
      const int d1 = 32 + quad * 8;
#pragma unroll
      for (int i = 0; i < 8; i++)
        qf1[i] = (short)f2bf((qp[d1 + i] + bqp[d1 + i]) * scale);
    } else {
#pragma unroll
      for (int i = 0; i < 8; i++) qf1[i] = 0;
    }
  }

  // staging geometry: 64 rows x 12 f32x4 = 768 vec4 = 3 per thread
  int sr[3], sc[3];
#pragma unroll
  for (int j = 0; j < 3; j++) { int i = tid + j * 256; sr[j] = i / 12; sc[j] = i % 12; }
  f32x4 kx[3], vx[3];

  // online softmax state per q-row (rows quad*4+r)
  float m[4], l[4];
#pragma unroll
  for (int r = 0; r < 4; r++) { m[r] = -1e30f; l[r] = 0.f; }
  f32x4 o0 = {0,0,0,0}, o1 = {0,0,0,0}, o2 = {0,0,0,0};

  // prologue: stage tile 0
#pragma unroll
  for (int j = 0; j < 3; j++) {
    const float* p = qkvg + (long)sr[j] * 3072 + h * 48 + sc[j] * 4;
    kx[j] = *(const f32x4*)(p + 768);
    vx[j] = *(const f32x4*)(p + 1536);
  }
#pragma unroll
  for (int j = 0; j < 3; j++) {
    short4v pk;
#pragma unroll
    for (int e = 0; e < 4; e++) pk[e] = (short)f2bf(kx[j][e]);
    *(short4v*)&Ks[0][sr[j]][sc[j] * 4] = pk;
#pragma unroll
    for (int e = 0; e < 4; e++) Vt[0][sc[j] * 4 + e][sr[j]] = f2bf(vx[j][e]);
  }

  const long bbase = ((long)h << 20) + (long)(q0 + w * 16 + quad * 4) * 1024 + lr;
  int cur = 0;

  for (int t = 0; t < 16; t++) {
    __syncthreads();
    // issue next tile's global loads early (latency hides under QK+softmax)
    if (t < 15) {
      const int kt = (t + 1) * 64;
#pragma unroll
      for (int j = 0; j < 3; j++) {
        const float* p = qkvg + (long)(kt + sr[j]) * 3072 + h * 48 + sc[j] * 4;
        kx[j] = *(const f32x4*)(p + 768);
        vx[j] = *(const f32x4*)(p + 1536);
      }
    }
    // bias loads for this tile
    u16 bw[16];
    const u16* bpt = biasb + bbase + t * 64;
#pragma unroll
    for (int j = 0; j < 4; j++)
#pragma unroll
      for (int r = 0; r < 4; r++)
        bw[j * 4 + r] = bpt[r * 1024 + j * 16];
    // QK^T: 4 key-col blocks x 2 k-steps
    f32x4 sv[4];
#pragma unroll
    for (int j = 0; j < 4; j++) {
      short8 kb0 = *(const short8*)&Ks[cur][j * 16 + lr][quad * 8];
      short8 kb1 = *(const short8*)&Ks[cur][j * 16 + lr][32 + quad * 8];
      f32x4 z = {0,0,0,0};
      z = __builtin_amdgcn_mfma_f32_16x16x32_bf16(qf0, kb0, z, 0, 0, 0);
      z = __builtin_amdgcn_mfma_f32_16x16x32_bf16(qf1, kb1, z, 0, 0, 0);
      sv[j] = z;
    }
#pragma unroll
    for (int j = 0; j < 4; j++)
#pragma unroll
      for (int r = 0; r < 4; r++)
        sv[j][r] += bf2f(bw[j * 4 + r]);
    // online softmax per q-row r (16-lane groups share a row set)
    float alpha[4];
#pragma unroll
    for (int r = 0; r < 4; r++) {
      float tmax = fmaxf(fmaxf(sv[0][r], sv[1][r]), fmaxf(sv[2][r], sv[3][r]));
      tmax = fmaxf(tmax, __shfl_xor(tmax, 1));
      tmax = fmaxf(tmax, __shfl_xor(tmax, 2));
      tmax = fmaxf(tmax, __shfl_xor(tmax, 4));
      tmax = fmaxf(tmax, __shfl_xor(tmax, 8));
      float mn = fmaxf(m[r], tmax);
      alpha[r] = __expf(m[r] - mn);
      m[r] = mn;
      float ps = 0.f;
#pragma unroll
      for (int j = 0; j < 4; j++) { float p = __expf(sv[j][r] - mn); sv[j][r] = p; ps += p; }
      ps += __shfl_xor(ps, 1); ps += __shfl_xor(ps, 2);
      ps += __shfl_xor(ps, 4); ps += __shfl_xor(ps, 8);
      l[r] = l[r] * alpha[r] + ps;
    }
    f32x4 al = {alpha[0], alpha[1], alpha[2], alpha[3]};
    o0 *= al; o1 *= al; o2 *= al;
    // P -> LDS (bf16), then PV via MFMA
#pragma unroll
    for (int j = 0; j < 4; j++)
#pragma unroll
      for (int r = 0; r < 4; r++)
        Ps[w][quad * 4 + r][j * 16 + lr] = f2bf(sv[j][r]);
#pragma unroll
    for (int kk = 0; kk < 2; kk++) {
      short8 pa  = *(const short8*)&Ps[w][lr][kk * 32 + quad * 8];
      short8 vb0 = *(const short8*)&Vt[cur][lr][kk * 32 + quad * 8];
      short8 vb1 = *(const short8*)&Vt[cur][16 + lr][kk * 32 + quad * 8];
      short8 vb2 = *(const short8*)&Vt[cur][32 + lr][kk * 32 + quad * 8];
      o0 = __builtin_amdgcn_mfma_f32_16x16x32_bf16(pa, vb0, o0, 0, 0, 0);
      o1 = __builtin_amdgcn_mfma_f32_16x16x32_bf16(pa, vb1, o1, 0, 0, 0);
      o2 = __builtin_amdgcn_mfma_f32_16x16x32_bf16(pa, vb2, o2, 0, 0, 0);
    }
    // write next tile into the other buffer (reads of it happen after next barrier)
    if (t < 15) {
      const int nb = cur ^ 1;
#pragma unroll
      for (int j = 0; j < 3; j++) {
        short4v pk;
#pragma unroll
        for (int e = 0; e < 4; e++) pk[e] = (short)f2bf(kx[j][e]);
        *(short4v*)&Ks[nb][sr[j]][sc[j] * 4] = pk;
#pragma unroll
        for (int e = 0; e < 4; e++) Vt[nb][sc[j] * 4 + e][sr[j]] = f2bf(vx[j][e]);
      }
    }
    cur ^= 1;
  }

  f32x4 linv = {1.f / l[0], 1.f / l[1], 1.f / l[2], 1.f / l[3]};
  o0 *= linv; o1 *= linv; o2 *= linv;
  const long ob = (long)(q0 + w * 16 + quad * 4) * 768 + h * 48 + lr;
#pragma unroll
  for (int r = 0; r < 4; r++) {
    o_out[ob + (long)r * 768]      = o0[r];
    o_out[ob + (long)r * 768 + 16] = o1[r];
    o_out[ob + (long)r * 768 + 32] = o2[r];
  }
}

// ---------------- gate * o -> bf16 ----------------
__launch_bounds__(256)
__global__ void k_gateo(const float* __restrict__ qkvg, const float* __restrict__ o,
                        u16* __restrict__ go) {
  int i = blockIdx.x * 256 + threadIdx.x;
  int c = i % 768; long m = i / 768;
  float g = qkvg[m * 3072 + 2304 + c];
  float sg = 1.f / (1.f + __expf(-g));
  go[i] = f2bf(sg * o[i]);
}

// ---------------- swiglu: hid = silu(h1) * h2 ----------------
__launch_bounds__(256)
__global__ void k_swiglu(const float* __restrict__ h12, u16* __restrict__ hid) {
  int i = blockIdx.x * 256 + threadIdx.x;  // over 1024*1536
  int c = i % 1536; long m = i / 1536;
  float x = h12[m * 3072 + c], y = h12[m * 3072 + 1536 + c];
  float si = x / (1.f + __expf(-x));
  hid[i] = f2bf(si * y);
}

// ---------------- final: sigmoid gates + sum (fp32 out) ----------------
__launch_bounds__(256)
__global__ void k_final(const float* __restrict__ sgr, const float* __restrict__ att_out,
                        const float* __restrict__ t3, const float* __restrict__ bso,
                        const float* __restrict__ bs2, float* __restrict__ out) {
  int i = blockIdx.x * 256 + threadIdx.x;
  int c = i % 768; long m = i / 768;
  float g1 = 1.f / (1.f + __expf(-(sgr[m * 1536 + c] + bso[c])));
  float g2 = 1.f / (1.f + __expf(-(sgr[m * 1536 + 768 + c] + bs2[c])));
  out[i] = g1 * att_out[i] + g2 * t3[i];
}

extern "C" void kernel_launch(void* const* d_in, const int* in_sizes, int n_in,
                              void* d_out, int out_size, void* d_ws, size_t ws_size,
                              hipStream_t stream) {
  const float* a    = (const float*)d_in[0];
  const float* s    = (const float*)d_in[1];
  const float* pair = (const float*)d_in[2];
  const float* beta = (const float*)d_in[3];
  const float* sg1  = (const float*)d_in[4];
  const float* wg1  = (const float*)d_in[5];
  const float* bg1  = (const float*)d_in[6];
  const float* wsk1 = (const float*)d_in[7];
  const float* wq   = (const float*)d_in[8];
  const float* bq   = (const float*)d_in[9];
  const float* wk   = (const float*)d_in[10];
  const float* wv   = (const float*)d_in[11];
  const float* gp   = (const float*)d_in[12];
  const float* bp   = (const float*)d_in[13];
  const float* wp   = (const float*)d_in[14];
  const float* wgate= (const float*)d_in[15];
  const float* wo   = (const float*)d_in[16];
  const float* wso  = (const float*)d_in[17];
  const float* bso  = (const float*)d_in[18];
  const float* sg2  = (const float*)d_in[19];
  const float* wg2  = (const float*)d_in[20];
  const float* bg2  = (const float*)d_in[21];
  const float* wsk2 = (const float*)d_in[22];
  const float* w1   = (const float*)d_in[23];
  const float* w2   = (const float*)d_in[24];
  const float* w3   = (const float*)d_in[25];
  const float* ws2  = (const float*)d_in[26];
  const float* bs2  = (const float*)d_in[27];

  char* ws = (char*)d_ws;
  const long E = 589824;  // 768*768
  u16* WT     = (u16*)ws;
  u16* wgsk1T = WT;            // [1536][768]
  u16* wgsk2T = WT + 2 * E;    // [1536][768]
  u16* wqkvgT = WT + 4 * E;    // [3072][768]
  u16* wsos2T = WT + 8 * E;    // [1536][768]
  u16* woT    = WT + 10 * E;   // [768][768]
  u16* w12T   = WT + 11 * E;   // [3072][768]
  u16* w3T    = WT + 15 * E;   // [768][1536]
  size_t off = 17 * E * 2;     // 20,054,016 B

  float* ln_a  = (float*)(ws + off); off += 786432 * 4;
  u16*   snb1  = (u16*)(ws + off);   off += 786432 * 2;
  u16*   snb2  = (u16*)(ws + off);   off += 786432 * 2;
  u16*   sb    = (u16*)(ws + off);   off += 786432 * 2;
  u16*   an1   = (u16*)(ws + off);   off += 786432 * 2;
  u16*   at2   = (u16*)(ws + off);   off += 786432 * 2;
  float* out12 = (float*)(ws + off); off += 1572864 * 4;
  float* out34 = (float*)(ws + off); off += 1572864 * 4;
  float* qkvg  = (float*)(ws + off); off += 3145728 * 4;
  float* h12   = qkvg;  // alias: qkvg dead after k_gateo; h12 written after
  float* o_buf = (float*)(ws + off); off += 786432 * 4;
  u16*   go    = (u16*)(ws + off);   off += 786432 * 2;
  float* att_o = (float*)(ws + off); off += 786432 * 4;
  float* sgr   = (float*)(ws + off); off += 1572864 * 4;
  u16*   hid   = (u16*)(ws + off);   off += 1572864 * 2;
  float* t3    = (float*)(ws + off); off += 786432 * 4;
  u16*   biasb = (u16*)(ws + off);   off += (long)16 * 1024 * 1024 * 2;

  TDescs td;
  td.d[0]  = {wg1,   wgsk1T,         768, 768};
  td.d[1]  = {wsk1,  wgsk1T + E,     768, 768};
  td.d[2]  = {wg2,   wgsk2T,         768, 768};
  td.d[3]  = {wsk2,  wgsk2T + E,     768, 768};
  td.d[4]  = {wq,    wqkvgT,         768, 768};
  td.d[5]  = {wk,    wqkvgT + E,     768, 768};
  td.d[6]  = {wv,    wqkvgT + 2 * E, 768, 768};
  td.d[7]  = {wgate, wqkvgT + 3 * E, 768, 768};
  td.d[8]  = {wso,   wsos2T,         768, 768};
  td.d[9]  = {ws2,   wsos2T + E,     768, 768};
  td.d[10] = {wo,    woT,            768, 768};
  td.d[11] = {w1,    w12T,           768, 1536};
  td.d[12] = {w2,    w12T + 2 * E,   768, 1536};
  td.d[13] = {w3,    w3T,            1536, 768};

  k_transpose<<<dim3(48, 48, 14), 256, 0, stream>>>(td);
  k_layernorm<<<1024, 256, 0, stream>>>(a, s, sg1, sg2, ln_a, snb1, snb2, sb);
  k_gemm_bt<<<dim3(24, 16), 256, 0, stream>>>(snb1, wgsk1T, out12, 1024, 1536, 768);
  k_gemm_bt<<<dim3(24, 16), 256, 0, stream>>>(snb2, wgsk2T, out34, 1024, 1536, 768);
  k_adaln2<<<3072, 256, 0, stream>>>(out12, out34, ln_a, bg1, bg2, an1, at2);
  k_gemm_bt<<<dim3(48, 16), 256, 0, stream>>>(an1, wqkvgT, qkvg, 1024, 3072, 768);
  k_pairbias<<<16384, 256, 0, stream>>>(pair, beta, gp, bp, wp, biasb);
  k_attention<<<dim3(16, 16), 256, 0, stream>>>(qkvg, bq, biasb, o_buf);
  k_gateo<<<3072, 256, 0, stream>>>(qkvg, o_buf, go);
  k_gemm_bt<<<dim3(12, 16), 256, 0, stream>>>(go, woT, att_o, 1024, 768, 768);
  k_gemm_bt<<<dim3(24, 16), 256, 0, stream>>>(sb, wsos2T, sgr, 1024, 1536, 768);
  k_gemm_bt<<<dim3(48, 16), 256, 0, stream>>>(at2, w12T, h12, 1024, 3072, 768);
  k_swiglu<<<6144, 256, 0, stream>>>(h12, hid);
  k_gemm_bt<<<dim3(12, 16), 256, 0, stream>>>(hid, w3T, t3, 1024, 768, 1536);
  k_final<<<3072, 256, 0, stream>>>(sgr, att_o, t3, bso, bs2, (float*)d_out);
}

// Round 2
// 926.172 us; speedup vs baseline: 1.2848x; 1.0415x over previous
//
#include <hip/hip_runtime.h>
#include <hip/hip_bf16.h>

typedef unsigned short u16;
typedef __attribute__((ext_vector_type(8))) short short8;
typedef __attribute__((ext_vector_type(4))) short short4v;
typedef __attribute__((ext_vector_type(4))) float f32x4;

__device__ __forceinline__ u16 f2bf(float f) {
  union { float f; unsigned int i; } v; v.f = f;
  unsigned int x = v.i;
  unsigned int r = x + 0x7fff + ((x >> 16) & 1);
  return (u16)(r >> 16);
}
__device__ __forceinline__ float bf2f(u16 u) {
  union { unsigned int i; float f; } v; v.i = ((unsigned int)u) << 16; return v.f;
}

// ---------------- transpose+convert: src fp32 [K][N] -> dst bf16 [N][K] ----------------
struct TDesc { const float* src; u16* dst; int K; int N; };
struct TDescs { TDesc d[14]; };

__launch_bounds__(256)
__global__ void k_transpose(TDescs td) {
  TDesc t = td.d[blockIdx.z];
  int tk = blockIdx.y * 32, tn = blockIdx.x * 32;
  if (tk >= t.K || tn >= t.N) return;
  __shared__ u16 tile[32][33];
  int tx = threadIdx.x & 31, ty = threadIdx.x >> 5; // 32 x 8
  for (int i = 0; i < 32; i += 8)
    tile[ty + i][tx] = f2bf(t.src[(long)(tk + ty + i) * t.N + tn + tx]);
  __syncthreads();
  for (int i = 0; i < 32; i += 8)
    t.dst[(long)(tn + ty + i) * t.K + tk + tx] = tile[tx][ty + i];
}

// ---------------- layernorm of a and s (rows of 768), + s->bf16 ----------------
__launch_bounds__(256)
__global__ void k_layernorm(const float* __restrict__ a, const float* __restrict__ s,
                            const float* __restrict__ sg1, const float* __restrict__ sg2,
                            float* __restrict__ ln_a, u16* __restrict__ snb1,
                            u16* __restrict__ snb2, u16* __restrict__ sb) {
  const int row = blockIdx.x, tid = threadIdx.x;
  const float* ar = a + (long)row * 768;
  const float* sr = s + (long)row * 768;
  float av[3], sv[3];
  float sa = 0.f, sa2 = 0.f, ss = 0.f, ss2 = 0.f;
  for (int i = 0; i < 3; i++) {
    float x = ar[tid + i * 256]; av[i] = x; sa += x; sa2 += x * x;
    float y = sr[tid + i * 256]; sv[i] = y; ss += y; ss2 += y * y;
  }
  __shared__ float red[4][4];
  for (int off = 32; off > 0; off >>= 1) {
    sa += __shfl_down(sa, off); sa2 += __shfl_down(sa2, off);
    ss += __shfl_down(ss, off); ss2 += __shfl_down(ss2, off);
  }
  if ((tid & 63) == 0) { int w = tid >> 6; red[w][0] = sa; red[w][1] = sa2; red[w][2] = ss; red[w][3] = ss2; }
  __syncthreads();
  sa  = red[0][0] + red[1][0] + red[2][0] + red[3][0];
  sa2 = red[0][1] + red[1][1] + red[2][1] + red[3][1];
  ss  = red[0][2] + red[1][2] + red[2][2] + red[3][2];
  ss2 = red[0][3] + red[1][3] + red[2][3] + red[3][3];
  const float n1 = 1.f / 768.f;
  float mua = sa * n1, vara = sa2 * n1 - mua * mua;
  float mus = ss * n1, vars = ss2 * n1 - mus * mus;
  float ra = rsqrtf(vara + 1e-5f), rs = rsqrtf(vars + 1e-5f);
  for (int i = 0; i < 3; i++) {
    int c = tid + i * 256;
    long idx = (long)row * 768 + c;
    ln_a[idx] = (av[i] - mua) * ra;
    float lns = (sv[i] - mus) * rs;
    snb1[idx] = f2bf(lns * sg1[c]);
    snb2[idx] = f2bf(lns * sg2[c]);
    sb[idx]   = f2bf(sv[i]);
  }
}

// ---------------- generic bf16 MFMA GEMM: C[M][N] = A[M][K] @ BT[N][K]^T ----------------
// 2-phase pipeline: double-buffered LDS, K-step 64, prefetch issued right after the
// single per-tile barrier, written to the alternate buffer after the MFMAs.
__launch_bounds__(256)
__global__ void k_gemm_bt(const u16* __restrict__ A, const u16* __restrict__ BT,
                          float* __restrict__ C, int M, int N, int K) {
  __shared__ u16 As[2][64][72];
  __shared__ u16 Bs[2][64][72];
  const int tid = threadIdx.x;
  const int n0 = blockIdx.x * 64, m0 = blockIdx.y * 64;
  const int wave = tid >> 6, lane = tid & 63;
  const int wr = (wave >> 1) * 32, wc = (wave & 1) * 32;
  const int lrow = lane & 15, quad = lane >> 4;
  // staging: 512 chunks of 8 bf16 per matrix; thread does chunks tid, tid+256
  const int r0 = tid >> 3, ck = (tid & 7) * 8;   // rows r0 and r0+32
  f32x4 acc00 = {0,0,0,0}, acc01 = {0,0,0,0}, acc10 = {0,0,0,0}, acc11 = {0,0,0,0};
  const u16* Ap0 = A + (long)(m0 + r0) * K + ck;
  const u16* Ap1 = A + (long)(m0 + r0 + 32) * K + ck;
  const u16* Bp0 = BT + (long)(n0 + r0) * K + ck;
  const u16* Bp1 = BT + (long)(n0 + r0 + 32) * K + ck;
  short8 a0v = *(const short8*)(Ap0), a1v = *(const short8*)(Ap1);
  short8 b0v = *(const short8*)(Bp0), b1v = *(const short8*)(Bp1);
  *(short8*)&As[0][r0][ck] = a0v; *(short8*)&As[0][r0 + 32][ck] = a1v;
  *(short8*)&Bs[0][r0][ck] = b0v; *(short8*)&Bs[0][r0 + 32][ck] = b1v;
  const int T = K >> 6;
  int cur = 0;
  for (int t = 0; t < T; t++) {
    __syncthreads();
    if (t + 1 < T) {
      const int ko = (t + 1) * 64;
      a0v = *(const short8*)(Ap0 + ko); a1v = *(const short8*)(Ap1 + ko);
      b0v = *(const short8*)(Bp0 + ko); b1v = *(const short8*)(Bp1 + ko);
    }
#pragma unroll
    for (int kk = 0; kk < 2; kk++) {
      short8 af0 = *(const short8*)&As[cur][wr + lrow][kk * 32 + quad * 8];
      short8 af1 = *(const short8*)&As[cur][wr + 16 + lrow][kk * 32 + quad * 8];
      short8 bf0 = *(const short8*)&Bs[cur][wc + lrow][kk * 32 + quad * 8];
      short8 bf1 = *(const short8*)&Bs[cur][wc + 16 + lrow][kk * 32 + quad * 8];
      acc00 = __builtin_amdgcn_mfma_f32_16x16x32_bf16(af0, bf0, acc00, 0, 0, 0);
      acc01 = __builtin_amdgcn_mfma_f32_16x16x32_bf16(af0, bf1, acc01, 0, 0, 0);
      acc10 = __builtin_amdgcn_mfma_f32_16x16x32_bf16(af1, bf0, acc10, 0, 0, 0);
      acc11 = __builtin_amdgcn_mfma_f32_16x16x32_bf16(af1, bf1, acc11, 0, 0, 0);
    }
    if (t + 1 < T) {
      const int nb = cur ^ 1;
      *(short8*)&As[nb][r0][ck] = a0v; *(short8*)&As[nb][r0 + 32][ck] = a1v;
      *(short8*)&Bs[nb][r0][ck] = b0v; *(short8*)&Bs[nb][r0 + 32][ck] = b1v;
    }
    cur ^= 1;
  }
  const int row = m0 + wr + quad * 4;
  const int col = n0 + wc + lrow;
  for (int r = 0; r < 4; r++) {
    C[(long)(row + r) * N + col]           = acc00[r];
    C[(long)(row + r) * N + col + 16]      = acc01[r];
    C[(long)(row + r + 16) * N + col]      = acc10[r];
    C[(long)(row + r + 16) * N + col + 16] = acc11[r];
  }
}

// ---------------- ada_ln epilogue for both branches ----------------
__launch_bounds__(256)
__global__ void k_adaln2(const float* __restrict__ g1, const float* __restrict__ g2,
                         const float* __restrict__ ln_a, const float* __restrict__ bg1,
                         const float* __restrict__ bg2, u16* __restrict__ an1,
                         u16* __restrict__ at2) {
  int i = blockIdx.x * 256 + threadIdx.x;  // over 1024*768
  int c = i % 768; long m = i / 768;
  float lna = ln_a[i];
  float x1 = g1[m * 1536 + c], y1 = g1[m * 1536 + 768 + c];
  float x2 = g2[m * 1536 + c], y2 = g2[m * 1536 + 768 + c];
  float s1 = 1.f / (1.f + __expf(-(x1 + bg1[c])));
  float s2 = 1.f / (1.f + __expf(-(x2 + bg2[c])));
  an1[i] = f2bf(s1 * lna + y1);
  at2[i] = f2bf(s2 * lna + y2);
}

// ---------------- pair bias via MFMA: bf16 [H][N][N] = (LN(pair)*gp+bp) @ wp + beta ----------------
__launch_bounds__(256)
__global__ void k_pairbias(const float* __restrict__ pair, const float* __restrict__ beta,
                           const float* __restrict__ gp, const float* __restrict__ bp,
                           const float* __restrict__ wp, u16* __restrict__ biasb) {
  __shared__ u16 Xs[64][136];
  __shared__ u16 Wb[16][136];
  __shared__ float Mu[64], Rs[64];
  __shared__ float AB[2][16];
  const int tid = threadIdx.x;
  const long base = (long)blockIdx.x * 64;
  // weights -> LDS
  for (int i = tid; i < 2048; i += 256) {
    int c = i >> 4, h = i & 15;
    Wb[h][c] = f2bf(gp[c] * wp[i]);
  }
  if (tid < 32) {
    int h = tid & 15;
    float acc = 0.f;
    if (tid < 16) { for (int c = 0; c < 128; c++) acc += gp[c] * wp[c * 16 + h]; }
    else          { for (int c = 0; c < 128; c++) acc += bp[c] * wp[c * 16 + h]; }
    AB[tid >> 4][h] = acc;
  }
  // stage X: 4 lanes per element, 32 floats each, coalesced f32x4
  const int e = tid >> 2, r = tid & 3;
  const float* px = pair + (base + e) * 128 + r * 4;
  float sum = 0.f, sq = 0.f;
  for (int p = 0; p < 8; p++) {
    f32x4 x = *(const f32x4*)(px + p * 16);
    sum += x[0] + x[1] + x[2] + x[3];
    sq  += x[0]*x[0] + x[1]*x[1] + x[2]*x[2] + x[3]*x[3];
    short4v pk;
    pk[0] = (short)f2bf(x[0]); pk[1] = (short)f2bf(x[1]);
    pk[2] = (short)f2bf(x[2]); pk[3] = (short)f2bf(x[3]);
    *(short4v*)&Xs[e][r * 4 + p * 16] = pk;
  }
  sum += __shfl_xor(sum, 1); sum += __shfl_xor(sum, 2);
  sq  += __shfl_xor(sq, 1);  sq  += __shfl_xor(sq, 2);
  if (r == 0) {
    float mu = sum * (1.f / 128.f);
    float var = sq * (1.f / 128.f) - mu * mu;
    Mu[e] = mu; Rs[e] = rsqrtf(var + 1e-5f);
  }
  __syncthreads();
  // MFMA: each wave does 16 elements x 16 heads, K=128
  const int wave = tid >> 6, lane = tid & 63;
  const int m = lane & 15, quad = lane >> 4;
  const int erow = wave * 16;
  f32x4 acc = {0, 0, 0, 0};
  for (int k0 = 0; k0 < 128; k0 += 32) {
    short8 af = *(const short8*)&Xs[erow + m][k0 + quad * 8];
    short8 bf = *(const short8*)&Wb[m][k0 + quad * 8];
    acc = __builtin_amdgcn_mfma_f32_16x16x32_bf16(af, bf, acc, 0, 0, 0);
  }
  // epilogue: C layout col=lane&15 (=h), row=quad*4+reg (=element)
  const int h = lane & 15;
  const float Ahv = AB[0][h], Bhv = AB[1][h];
  const int e0 = erow + quad * 4;
  short4v outp;
  for (int rr = 0; rr < 4; rr++) {
    int ee = e0 + rr;
    float bt = beta[base + ee];
    float val = Rs[ee] * acc[rr] - Rs[ee] * Mu[ee] * Ahv + Bhv + bt;
    outp[rr] = (short)f2bf(val);
  }
  *(short4v*)&biasb[((long)h << 20) + base + e0] = outp;
}

// ---------------- attention: MFMA flash, 64 q-rows/block (4 waves x 16), 64-key tiles ----------------
// Fused output gate: writes go = bf16(sigmoid(gate) * o) directly.
__launch_bounds__(256)
__global__ void k_attention(const float* __restrict__ qkvg, const float* __restrict__ bq,
                            const u16* __restrict__ biasb, u16* __restrict__ go) {
  const int h = blockIdx.y;
  const int q0 = blockIdx.x * 64;
  __shared__ u16 Ks[2][64][72];   // [buf][key][d]
  __shared__ u16 Vt[2][48][72];   // [buf][d][key]  (transposed V)
  __shared__ u16 Ps[4][16][72];   // per-wave P tile [q][key]
  const int tid = threadIdx.x;
  const int w = tid >> 6, lane = tid & 63;
  const int lr = lane & 15, quad = lane >> 4;
  const float scale = 0.14433756729740643f;  // 1/sqrt(48)

  // zero K pad cols 48..63 for both buffers
  for (int i = tid; i < 2 * 64 * 16; i += 256) {
    int b = i >> 10, rr = (i >> 4) & 63, c = 48 + (i & 15);
    Ks[b][rr][c] = 0;
  }

  // Q fragments in registers (A-operand, rows = q0 + w*16 + lr)
  short8 qf0, qf1;
  {
    const int qrow = q0 + w * 16 + lr;
    const float* qp = qkvg + (long)qrow * 3072 + h * 48;
    const float* bqp = bq + h * 48;
    const int d0 = quad * 8;
#pragma unroll
    for (int i = 0; i < 8; i++)
      qf0[i] = (short)f2bf((qp[d0 + i] + bqp[d0 + i]) * scale);
    if (quad < 2) {
      const int d1 = 32 + quad * 8;
#pragma unroll
      for (int i = 0; i < 8; i++)
        qf1[i] = (short)f2bf((qp[d1 + i] + bqp[d1 + i]) * scale);
    } else {
#pragma unroll
      for (int i = 0; i < 8; i++) qf1[i] = 0;
    }
  }

  // staging geometry: 64 rows x 12 f32x4 = 768 vec4 = 3 per thread
  int sr[3], sc[3];
#pragma unroll
  for (int j = 0; j < 3; j++) { int i = tid + j * 256; sr[j] = i / 12; sc[j] = i % 12; }
  f32x4 kx[3], vx[3];

  // online softmax state per q-row (rows quad*4+r)
  float m[4], l[4];
#pragma unroll
  for (int r = 0; r < 4; r++) { m[r] = -1e30f; l[r] = 0.f; }
  f32x4 o0 = {0,0,0,0}, o1 = {0,0,0,0}, o2 = {0,0,0,0};

  // prologue: stage tile 0
#pragma unroll
  for (int j = 0; j < 3; j++) {
    const float* p = qkvg + (long)sr[j] * 3072 + h * 48 + sc[j] * 4;
    kx[j] = *(const f32x4*)(p + 768);
    vx[j] = *(const f32x4*)(p + 1536);
  }
#pragma unroll
  for (int j = 0; j < 3; j++) {
    short4v pk;
#pragma unroll
    for (int e = 0; e < 4; e++) pk[e] = (short)f2bf(kx[j][e]);
    *(short4v*)&Ks[0][sr[j]][sc[j] * 4] = pk;
#pragma unroll
    for (int e = 0; e < 4; e++) Vt[0][sc[j] * 4 + e][sr[j]] = f2bf(vx[j][e]);
  }

  const long bbase = ((long)h << 20) + (long)(q0 + w * 16 + quad * 4) * 1024 + lr;
  int cur = 0;

  for (int t = 0; t < 16; t++) {
    __syncthreads();
    // issue next tile's global loads early (latency hides under QK+softmax)
    if (t < 15) {
      const int kt = (t + 1) * 64;
#pragma unroll
      for (int j = 0; j < 3; j++) {
        const float* p = qkvg + (long)(kt + sr[j]) * 3072 + h * 48 + sc[j] * 4;
        kx[j] = *(const f32x4*)(p + 768);
        vx[j] = *(const f32x4*)(p + 1536);
      }
    }
    // bias loads for this tile
    u16 bw[16];
    const u16* bpt = biasb + bbase + t * 64;
#pragma unroll
    for (int j = 0; j < 4; j++)
#pragma unroll
      for (int r = 0; r < 4; r++)
        bw[j * 4 + r] = bpt[r * 1024 + j * 16];
    // QK^T: 4 key-col blocks x 2 k-steps
    f32x4 sv[4];
#pragma unroll
    for (int j = 0; j < 4; j++) {
      short8 kb0 = *(const short8*)&Ks[cur][j * 16 + lr][quad * 8];
      short8 kb1 = *(const short8*)&Ks[cur][j * 16 + lr][32 + quad * 8];
      f32x4 z = {0,0,0,0};
      z = __builtin_amdgcn_mfma_f32_16x16x32_bf16(qf0, kb0, z, 0, 0, 0);
      z = __builtin_amdgcn_mfma_f32_16x16x32_bf16(qf1, kb1, z, 0, 0, 0);
      sv[j] = z;
    }
#pragma unroll
    for (int j = 0; j < 4; j++)
#pragma unroll
      for (int r = 0; r < 4; r++)
        sv[j][r] += bf2f(bw[j * 4 + r]);
    // online softmax per q-row r (16-lane groups share a row set)
    float alpha[4];
#pragma unroll
    for (int r = 0; r < 4; r++) {
      float tmax = fmaxf(fmaxf(sv[0][r], sv[1][r]), fmaxf(sv[2][r], sv[3][r]));
      tmax = fmaxf(tmax, __shfl_xor(tmax, 1));
      tmax = fmaxf(tmax, __shfl_xor(tmax, 2));
      tmax = fmaxf(tmax, __shfl_xor(tmax, 4));
      tmax = fmaxf(tmax, __shfl_xor(tmax, 8));
      float mn = fmaxf(m[r], tmax);
      alpha[r] = __expf(m[r] - mn);
      m[r] = mn;
      float ps = 0.f;
#pragma unroll
      for (int j = 0; j < 4; j++) { float p = __expf(sv[j][r] - mn); sv[j][r] = p; ps += p; }
      ps += __shfl_xor(ps, 1); ps += __shfl_xor(ps, 2);
      ps += __shfl_xor(ps, 4); ps += __shfl_xor(ps, 8);
      l[r] = l[r] * alpha[r] + ps;
    }
    f32x4 al = {alpha[0], alpha[1], alpha[2], alpha[3]};
    o0 *= al; o1 *= al; o2 *= al;
    // P -> LDS (bf16), then PV via MFMA
#pragma unroll
    for (int j = 0; j < 4; j++)
#pragma unroll
      for (int r = 0; r < 4; r++)
        Ps[w][quad * 4 + r][j * 16 + lr] = f2bf(sv[j][r]);
#pragma unroll
    for (int kk = 0; kk < 2; kk++) {
      short8 pa  = *(const short8*)&Ps[w][lr][kk * 32 + quad * 8];
      short8 vb0 = *(const short8*)&Vt[cur][lr][kk * 32 + quad * 8];
      short8 vb1 = *(const short8*)&Vt[cur][16 + lr][kk * 32 + quad * 8];
      short8 vb2 = *(const short8*)&Vt[cur][32 + lr][kk * 32 + quad * 8];
      o0 = __builtin_amdgcn_mfma_f32_16x16x32_bf16(pa, vb0, o0, 0, 0, 0);
      o1 = __builtin_amdgcn_mfma_f32_16x16x32_bf16(pa, vb1, o1, 0, 0, 0);
      o2 = __builtin_amdgcn_mfma_f32_16x16x32_bf16(pa, vb2, o2, 0, 0, 0);
    }
    // write next tile into the other buffer (reads of it happen after next barrier)
    if (t < 15) {
      const int nb = cur ^ 1;
#pragma unroll
      for (int j = 0; j < 3; j++) {
        short4v pk;
#pragma unroll
        for (int e = 0; e < 4; e++) pk[e] = (short)f2bf(kx[j][e]);
        *(short4v*)&Ks[nb][sr[j]][sc[j] * 4] = pk;
#pragma unroll
        for (int e = 0; e < 4; e++) Vt[nb][sc[j] * 4 + e][sr[j]] = f2bf(vx[j][e]);
      }
    }
    cur ^= 1;
  }

  // epilogue: normalize, apply sigmoid(gate), write bf16 go
  const int qrow0 = q0 + w * 16 + quad * 4;
  const int colb = h * 48 + lr;
#pragma unroll
  for (int r = 0; r < 4; r++) {
    const int row = qrow0 + r;
    const float inv = 1.f / l[r];
    const float* gpt = qkvg + (long)row * 3072 + 2304 + colb;
    float g0 = 1.f / (1.f + __expf(-gpt[0]));
    float g1 = 1.f / (1.f + __expf(-gpt[16]));
    float g2 = 1.f / (1.f + __expf(-gpt[32]));
    u16* gop = go + (long)row * 768 + colb;
    gop[0]  = f2bf(g0 * o0[r] * inv);
    gop[16] = f2bf(g1 * o1[r] * inv);
    gop[32] = f2bf(g2 * o2[r] * inv);
  }
}

// ---------------- swiglu: hid = silu(h1) * h2 ----------------
__launch_bounds__(256)
__global__ void k_swiglu(const float* __restrict__ h12, u16* __restrict__ hid) {
  int i = blockIdx.x * 256 + threadIdx.x;  // over 1024*1536
  int c = i % 1536; long m = i / 1536;
  float x = h12[m * 3072 + c], y = h12[m * 3072 + 1536 + c];
  float si = x / (1.f + __expf(-x));
  hid[i] = f2bf(si * y);
}

// ---------------- final: sigmoid gates + sum (fp32 out) ----------------
__launch_bounds__(256)
__global__ void k_final(const float* __restrict__ sgr, const float* __restrict__ att_out,
                        const float* __restrict__ t3, const float* __restrict__ bso,
                        const float* __restrict__ bs2, float* __restrict__ out) {
  int i = blockIdx.x * 256 + threadIdx.x;
  int c = i % 768; long m = i / 768;
  float g1 = 1.f / (1.f + __expf(-(sgr[m * 1536 + c] + bso[c])));
  float g2 = 1.f / (1.f + __expf(-(sgr[m * 1536 + 768 + c] + bs2[c])));
  out[i] = g1 * att_out[i] + g2 * t3[i];
}

extern "C" void kernel_launch(void* const* d_in, const int* in_sizes, int n_in,
                              void* d_out, int out_size, void* d_ws, size_t ws_size,
                              hipStream_t stream) {
  const float* a    = (const float*)d_in[0];
  const float* s    = (const float*)d_in[1];
  const float* pair = (const float*)d_in[2];
  const float* beta = (const float*)d_in[3];
  const float* sg1  = (const float*)d_in[4];
  const float* wg1  = (const float*)d_in[5];
  const float* bg1  = (const float*)d_in[6];
  const float* wsk1 = (const float*)d_in[7];
  const float* wq   = (const float*)d_in[8];
  const float* bq   = (const float*)d_in[9];
  const float* wk   = (const float*)d_in[10];
  const float* wv   = (const float*)d_in[11];
  const float* gp   = (const float*)d_in[12];
  const float* bp   = (const float*)d_in[13];
  const float* wp   = (const float*)d_in[14];
  const float* wgate= (const float*)d_in[15];
  const float* wo   = (const float*)d_in[16];
  const float* wso  = (const float*)d_in[17];
  const float* bso  = (const float*)d_in[18];
  const float* sg2  = (const float*)d_in[19];
  const float* wg2  = (const float*)d_in[20];
  const float* bg2  = (const float*)d_in[21];
  const float* wsk2 = (const float*)d_in[22];
  const float* w1   = (const float*)d_in[23];
  const float* w2   = (const float*)d_in[24];
  const float* w3   = (const float*)d_in[25];
  const float* ws2  = (const float*)d_in[26];
  const float* bs2  = (const float*)d_in[27];

  char* ws = (char*)d_ws;
  const long E = 589824;  // 768*768
  u16* WT     = (u16*)ws;
  u16* wgsk1T = WT;            // [1536][768]
  u16* wgsk2T = WT + 2 * E;    // [1536][768]
  u16* wqkvgT = WT + 4 * E;    // [3072][768]
  u16* wsos2T = WT + 8 * E;    // [1536][768]
  u16* woT    = WT + 10 * E;   // [768][768]
  u16* w12T   = WT + 11 * E;   // [3072][768]
  u16* w3T    = WT + 15 * E;   // [768][1536]
  size_t off = 17 * E * 2;     // 20,054,016 B

  float* ln_a  = (float*)(ws + off); off += 786432 * 4;
  u16*   snb1  = (u16*)(ws + off);   off += 786432 * 2;
  u16*   snb2  = (u16*)(ws + off);   off += 786432 * 2;
  u16*   sb    = (u16*)(ws + off);   off += 786432 * 2;
  u16*   an1   = (u16*)(ws + off);   off += 786432 * 2;
  u16*   at2   = (u16*)(ws + off);   off += 786432 * 2;
  float* out12 = (float*)(ws + off); off += 1572864 * 4;
  float* out34 = (float*)(ws + off); off += 1572864 * 4;
  float* qkvg  = (float*)(ws + off); off += 3145728 * 4;
  float* h12   = qkvg;  // alias: qkvg dead after k_attention; h12 written after
  u16*   go    = (u16*)(ws + off);   off += 786432 * 2;
  float* att_o = (float*)(ws + off); off += 786432 * 4;
  float* sgr   = (float*)(ws + off); off += 1572864 * 4;
  u16*   hid   = (u16*)(ws + off);   off += 1572864 * 2;
  float* t3    = (float*)(ws + off); off += 786432 * 4;
  u16*   biasb = (u16*)(ws + off);   off += (long)16 * 1024 * 1024 * 2;

  TDescs td;
  td.d[0]  = {wg1,   wgsk1T,         768, 768};
  td.d[1]  = {wsk1,  wgsk1T + E,     768, 768};
  td.d[2]  = {wg2,   wgsk2T,         768, 768};
  td.d[3]  = {wsk2,  wgsk2T + E,     768, 768};
  td.d[4]  = {wq,    wqkvgT,         768, 768};
  td.d[5]  = {wk,    wqkvgT + E,     768, 768};
  td.d[6]  = {wv,    wqkvgT + 2 * E, 768, 768};
  td.d[7]  = {wgate, wqkvgT + 3 * E, 768, 768};
  td.d[8]  = {wso,   wsos2T,         768, 768};
  td.d[9]  = {ws2,   wsos2T + E,     768, 768};
  td.d[10] = {wo,    woT,            768, 768};
  td.d[11] = {w1,    w12T,           768, 1536};
  td.d[12] = {w2,    w12T + 2 * E,   768, 1536};
  td.d[13] = {w3,    w3T,            1536, 768};

  k_transpose<<<dim3(48, 48, 14), 256, 0, stream>>>(td);
  k_layernorm<<<1024, 256, 0, stream>>>(a, s, sg1, sg2, ln_a, snb1, snb2, sb);
  k_gemm_bt<<<dim3(24, 16), 256, 0, stream>>>(snb1, wgsk1T, out12, 1024, 1536, 768);
  k_gemm_bt<<<dim3(24, 16), 256, 0, stream>>>(snb2, wgsk2T, out34, 1024, 1536, 768);
  k_adaln2<<<3072, 256, 0, stream>>>(out12, out34, ln_a, bg1, bg2, an1, at2);
  k_gemm_bt<<<dim3(48, 16), 256, 0, stream>>>(an1, wqkvgT, qkvg, 1024, 3072, 768);
  k_pairbias<<<16384, 256, 0, stream>>>(pair, beta, gp, bp, wp, biasb);
  k_attention<<<dim3(16, 16), 256, 0, stream>>>(qkvg, bq, biasb, go);
  k_gemm_bt<<<dim3(12, 16), 256, 0, stream>>>(go, woT, att_o, 1024, 768, 768);
  k_gemm_bt<<<dim3(24, 16), 256, 0, stream>>>(sb, wsos2T, sgr, 1024, 1536, 768);
  k_gemm_bt<<<dim3(48, 16), 256, 0, stream>>>(at2, w12T, h12, 1024, 3072, 768);
  k_swiglu<<<6144, 256, 0, stream>>>(h12, hid);
  k_gemm_bt<<<dim3(12, 16), 256, 0, stream>>>(hid, w3T, t3, 1024, 768, 1536);
  k_final<<<3072, 256, 0, stream>>>(sgr, att_o, t3, bso, bs2, (float*)d_out);
}